// Round 7
// baseline (225.534 us; speedup 1.0000x reference)
//
#include <hip/hip_runtime.h>

// SoftAttention: B=4, Q=64, S=1024, H=512, fp32.
// out = [context (B*Q*H)] ++ [weights (B*Q*S)]
// ws: qp [256*512] at 0; kp [4096*512] at +512KB; context partials alias kp.
// qp/kp hold (2*log2e)*(X@W+b): score uses exp2(qp+kp) = exp(2*(q+k)).
// be cancels in softmax.  r5 lesson: NO global atomics for partial sums.
// r6 lesson: per-CU LDS issue (~12cyc/b128, shared by 4 SIMDs) limits GEMM;
// maximize FMA per ds_read -> 8x8 micro-tile, ~2 waves/CU.

constexpr int kB = 4;
constexpr int kQ = 64;
constexpr int kS = 1024;
constexpr int kH = 512;
constexpr float kScale = 2.8853900817779268f;  // 2*log2(e)

// ---------------------------------------------------------------------------
// Projection: Y = kScale*(X[M,512] @ W[512,512] + bias).
// 64-thread (1-wave) blocks, 64x64 tile, 8x8 acc/thread, K-chunk 32 dbuf.
// grid = (8 col-tiles, 68 row-tiles: 64 kp + 4 qp) = 544 blocks (~2.1 waves/CU).
// Per kk: 4 ds_read_b128 (48 pipe-cyc) per 64 FMA (128 VALU-cyc): 2 waves fit.
// ---------------------------------------------------------------------------
constexpr int kPC = 32;   // K-chunk
constexpr int kPS = 68;   // LDS row stride (floats)

__global__ __launch_bounds__(64, 2) void proj_dual(
    const float* __restrict__ Xk, const float* __restrict__ Wk,
    const float* __restrict__ bk, float* __restrict__ Yk,
    const float* __restrict__ Xq, const float* __restrict__ Wq,
    const float* __restrict__ bq, float* __restrict__ Yq) {
  __shared__ __align__(16) float As[2][kPC * kPS];  // [k][row]
  __shared__ __align__(16) float Bs[2][kPC * kPS];  // [k][col]
  const int t = threadIdx.x;  // 0..63
  const int ct = blockIdx.x;  // 0..7
  int rt = blockIdx.y;        // 0..67
  const float *X, *W, *bias;
  float* Y;
  if (rt < 64) {
    X = Xk + (size_t)rt * 64 * kH; W = Wk; bias = bk; Y = Yk + (size_t)rt * 64 * kH;
  } else {
    rt -= 64;
    X = Xq + (size_t)rt * 64 * kH; W = Wq; bias = bq; Y = Yq + (size_t)rt * 64 * kH;
  }

  const int cbase = ct * 64;
  // B staging: k = t>>1 (0..31), c = (t&1)*32, 8 float4 per thread
  const int b_k = t >> 1;
  const int b_c = (t & 1) * 32;
  // Compute mapping: 8 rows x 8 cols per thread
  const int r0 = (t >> 3) * 8;
  const int c0 = (t & 7) * 8;

  float4 pa[8], pb[8];

  auto gload = [&](int kb) {
    const float* xp = X + (size_t)t * kH + kb;  // A: row t, 32 k's
#pragma unroll
    for (int j = 0; j < 8; j++) pa[j] = *(const float4*)(xp + 4 * j);
    const float* wp = W + (size_t)(kb + b_k) * kH + cbase + b_c;
#pragma unroll
    for (int j = 0; j < 8; j++) pb[j] = *(const float4*)(wp + 4 * j);
  };

  auto lwrite = [&](int buf) {
    float* a = As[buf];
#pragma unroll
    for (int j = 0; j < 8; j++) {  // transpose: As[k][row]
      a[(4 * j + 0) * kPS + t] = pa[j].x;
      a[(4 * j + 1) * kPS + t] = pa[j].y;
      a[(4 * j + 2) * kPS + t] = pa[j].z;
      a[(4 * j + 3) * kPS + t] = pa[j].w;
    }
    float* bl = Bs[buf] + b_k * kPS + b_c;
#pragma unroll
    for (int j = 0; j < 8; j++) *(float4*)(bl + 4 * j) = pb[j];
  };

  float4 acc[8][2];
#pragma unroll
  for (int i = 0; i < 8; i++) {
    acc[i][0] = {0, 0, 0, 0};
    acc[i][1] = {0, 0, 0, 0};
  }

  gload(0);
  lwrite(0);
  __syncthreads();

  for (int kc = 0; kc < 16; kc++) {
    if (kc < 15) gload((kc + 1) * kPC);

    const float* a = As[kc & 1];
    const float* bsp = Bs[kc & 1];
#pragma unroll 4
    for (int kk = 0; kk < kPC; kk++) {
      float4 a0 = *(const float4*)(a + kk * kPS + r0);
      float4 a1 = *(const float4*)(a + kk * kPS + r0 + 4);
      float4 b0 = *(const float4*)(bsp + kk * kPS + c0);
      float4 b1 = *(const float4*)(bsp + kk * kPS + c0 + 4);
      float ar[8] = {a0.x, a0.y, a0.z, a0.w, a1.x, a1.y, a1.z, a1.w};
#pragma unroll
      for (int i = 0; i < 8; i++) {
        acc[i][0].x = fmaf(ar[i], b0.x, acc[i][0].x);
        acc[i][0].y = fmaf(ar[i], b0.y, acc[i][0].y);
        acc[i][0].z = fmaf(ar[i], b0.z, acc[i][0].z);
        acc[i][0].w = fmaf(ar[i], b0.w, acc[i][0].w);
        acc[i][1].x = fmaf(ar[i], b1.x, acc[i][1].x);
        acc[i][1].y = fmaf(ar[i], b1.y, acc[i][1].y);
        acc[i][1].z = fmaf(ar[i], b1.z, acc[i][1].z);
        acc[i][1].w = fmaf(ar[i], b1.w, acc[i][1].w);
      }
    }

    if (kc < 15) {
      __syncthreads();
      lwrite((kc + 1) & 1);
      __syncthreads();
    }
  }

  float4 bv0 = *(const float4*)(bias + cbase + c0);
  float4 bv1 = *(const float4*)(bias + cbase + c0 + 4);
#pragma unroll
  for (int i = 0; i < 8; i++) {
    float* yp = Y + (size_t)(r0 + i) * kH + cbase + c0;
    float4 o;
    o.x = kScale * (acc[i][0].x + bv0.x);
    o.y = kScale * (acc[i][0].y + bv0.y);
    o.z = kScale * (acc[i][0].z + bv0.z);
    o.w = kScale * (acc[i][0].w + bv0.w);
    *(float4*)(yp) = o;
    o.x = kScale * (acc[i][1].x + bv1.x);
    o.y = kScale * (acc[i][1].y + bv1.y);
    o.z = kScale * (acc[i][1].z + bv1.z);
    o.w = kScale * (acc[i][1].w + bv1.w);
    *(float4*)(yp + 4) = o;
  }
}

// ---------------------------------------------------------------------------
// Scores (raw) -> sout[bq][s].  tanh(x) = 1 - 2*rcp(1+exp(2x));
// qp/kp pre-scaled by 2*log2e so exp(2(q+k)) = exp2(qp+kp).
// sum we*tanh = sum_we + sum (-2*we)*rcp(1+exp2(qp+kp)).
// grid = 1024 (b x 8 q-tiles x 32 s-chunks), 256 thr = 4 waves, 8 s/wave,
// 8 q per wave.  Trans-pipe-bound (128 trans ops per si per lane-row).
// ---------------------------------------------------------------------------
__global__ __launch_bounds__(256) void score_kernel(
    const float* __restrict__ qp, const float* __restrict__ kp,
    const float* __restrict__ we, float* __restrict__ sout) {
  const int bx = blockIdx.x;
  const int b = bx >> 8, qt = (bx >> 5) & 7, st = bx & 31;
  const int t = threadIdx.x, wave = t >> 6, lane = t & 63;

  const float4* we4 = (const float4*)(we + lane * 8);
  float4 w0 = we4[0], w1 = we4[1];
  float wsum = w0.x + w0.y + w0.z + w0.w + w1.x + w1.y + w1.z + w1.w;
#pragma unroll
  for (int off = 32; off; off >>= 1) wsum += __shfl_xor(wsum, off);
  w0.x *= -2.f; w0.y *= -2.f; w0.z *= -2.f; w0.w *= -2.f;
  w1.x *= -2.f; w1.y *= -2.f; w1.z *= -2.f; w1.w *= -2.f;

  const int q0 = qt * 8;
  float4 qv[8][2];
#pragma unroll
  for (int i = 0; i < 8; i++) {
    const float4* q4 = (const float4*)(qp + (size_t)(b * kQ + q0 + i) * kH + lane * 8);
    qv[i][0] = q4[0]; qv[i][1] = q4[1];
  }

  const int sbase = st * 32 + wave * 8;
  const float* kbase = kp + ((size_t)b * kS + sbase) * kH + lane * 8;

  float4 k0 = *(const float4*)(kbase);
  float4 k1 = *(const float4*)(kbase + 4);

  for (int si = 0; si < 8; si++) {
    float4 n0, n1;
    if (si < 7) {
      const float* np = kbase + (size_t)(si + 1) * kH;
      n0 = *(const float4*)(np);
      n1 = *(const float4*)(np + 4);
    }
    float a[8];
#pragma unroll
    for (int i = 0; i < 8; i++) {
      float acc = 0.f, e;
      e = exp2f(qv[i][0].x + k0.x); acc = fmaf(w0.x, __builtin_amdgcn_rcpf(1.f + e), acc);
      e = exp2f(qv[i][0].y + k0.y); acc = fmaf(w0.y, __builtin_amdgcn_rcpf(1.f + e), acc);
      e = exp2f(qv[i][0].z + k0.z); acc = fmaf(w0.z, __builtin_amdgcn_rcpf(1.f + e), acc);
      e = exp2f(qv[i][0].w + k0.w); acc = fmaf(w0.w, __builtin_amdgcn_rcpf(1.f + e), acc);
      e = exp2f(qv[i][1].x + k1.x); acc = fmaf(w1.x, __builtin_amdgcn_rcpf(1.f + e), acc);
      e = exp2f(qv[i][1].y + k1.y); acc = fmaf(w1.y, __builtin_amdgcn_rcpf(1.f + e), acc);
      e = exp2f(qv[i][1].z + k1.z); acc = fmaf(w1.z, __builtin_amdgcn_rcpf(1.f + e), acc);
      e = exp2f(qv[i][1].w + k1.w); acc = fmaf(w1.w, __builtin_amdgcn_rcpf(1.f + e), acc);
      a[i] = acc;
    }
#pragma unroll
    for (int i = 0; i < 8; i++) {
#pragma unroll
      for (int off = 32; off; off >>= 1) a[i] += __shfl_xor(a[i], off);
    }
    if (lane == 0) {
      const int s = sbase + si;
#pragma unroll
      for (int i = 0; i < 8; i++)
        sout[(size_t)(b * kQ + q0 + i) * kS + s] = a[i] + wsum;
    }
    k0 = n0; k1 = n1;
  }
}

// ---------------------------------------------------------------------------
// Softmax in place on wout rows of 1024.  grid = 256 rows, 256 thr.
// ---------------------------------------------------------------------------
__global__ __launch_bounds__(256) void softmax_kernel(float* __restrict__ wout) {
  __shared__ float redm[4];
  __shared__ float reds[4];
  const int row = blockIdx.x;
  const int t = threadIdx.x, wave = t >> 6, lane = t & 63;
  float4* rp = (float4*)(wout + (size_t)row * kS);
  float4 v = rp[t];

  float m = fmaxf(fmaxf(v.x, v.y), fmaxf(v.z, v.w));
#pragma unroll
  for (int off = 32; off; off >>= 1) m = fmaxf(m, __shfl_xor(m, off));
  if (lane == 0) redm[wave] = m;
  __syncthreads();
  m = fmaxf(fmaxf(redm[0], redm[1]), fmaxf(redm[2], redm[3]));

  float4 e;
  e.x = __expf(v.x - m); e.y = __expf(v.y - m);
  e.z = __expf(v.z - m); e.w = __expf(v.w - m);
  float sum = e.x + e.y + e.z + e.w;
#pragma unroll
  for (int off = 32; off; off >>= 1) sum += __shfl_xor(sum, off);
  if (lane == 0) reds[wave] = sum;
  __syncthreads();
  sum = reds[0] + reds[1] + reds[2] + reds[3];
  float inv = 1.f / sum;
  e.x *= inv; e.y *= inv; e.z *= inv; e.w *= inv;
  rp[t] = e;
}

// ---------------------------------------------------------------------------
// Context partials, LDS-free: weights read via wave-uniform addresses
// (compiler -> s_load_dwordx4), V-loads coalesced.  acc[32]/thread.
// grid = 256 (b x 2 hc x 2 qc x 16 sc), 256 thr; s-chunk 64, q-chunk 32.
// part[sc][bq][h] = sum_{s in chunk} w[bq][s] * value[b][s][h]
// ---------------------------------------------------------------------------
__global__ __launch_bounds__(256) void context_kernel(
    const float* __restrict__ wout, const float* __restrict__ value,
    float* __restrict__ part) {
  const int bx = blockIdx.x;
  const int sc = bx & 15, qc = (bx >> 4) & 1, hc = (bx >> 5) & 1, b = bx >> 6;
  const int t = threadIdx.x;
  const int s0 = sc * 64, q0 = qc * 32;
  const int h = hc * 256 + t;

  const float* wp = wout + (size_t)(b * kQ + q0) * kS + s0;  // wave-uniform
  const float* vb = value + ((size_t)b * kS + s0) * kH + h;

  float acc[32];
#pragma unroll
  for (int q = 0; q < 32; q++) acc[q] = 0.f;

  for (int sg = 0; sg < 16; sg++) {  // 64 s in groups of 4
    const float* vg = vb + (size_t)sg * 4 * kH;
    float v0 = vg[0 * kH];
    float v1 = vg[1 * kH];
    float v2 = vg[2 * kH];
    float v3 = vg[3 * kH];
#pragma unroll
    for (int q = 0; q < 32; q++) {
      float4 w = *(const float4*)(wp + (size_t)q * kS + sg * 4);  // s_load_dwordx4
      acc[q] = fmaf(w.x, v0, acc[q]);
      acc[q] = fmaf(w.y, v1, acc[q]);
      acc[q] = fmaf(w.z, v2, acc[q]);
      acc[q] = fmaf(w.w, v3, acc[q]);
    }
  }

  float* pp = part + (size_t)sc * kB * kQ * kH;
#pragma unroll
  for (int q = 0; q < 32; q++)
    pp[(size_t)(b * kQ + q0 + q) * kH + h] = acc[q];
}

// ctx[i] = sum over 16 s-chunk partials.  grid = 128, 256 thr.
__global__ __launch_bounds__(256) void reduce_kernel(
    const float* __restrict__ part, float* __restrict__ ctx) {
  const int i = blockIdx.x * 256 + threadIdx.x;  // float4 index, 32768 total
  float4 a = {0, 0, 0, 0};
#pragma unroll
  for (int p = 0; p < 16; p++) {
    float4 v = ((const float4*)(part + (size_t)p * kB * kQ * kH))[i];
    a.x += v.x; a.y += v.y; a.z += v.z; a.w += v.w;
  }
  ((float4*)ctx)[i] = a;
}

extern "C" void kernel_launch(void* const* d_in, const int* in_sizes, int n_in,
                              void* d_out, int out_size, void* d_ws,
                              size_t ws_size, hipStream_t stream) {
  const float* query = (const float*)d_in[0];
  const float* key_  = (const float*)d_in[1];
  const float* value = (const float*)d_in[2];
  const float* Wq    = (const float*)d_in[3];
  const float* bq    = (const float*)d_in[4];
  const float* Wk    = (const float*)d_in[5];
  const float* bk    = (const float*)d_in[6];
  const float* we    = (const float*)d_in[7];
  // be (d_in[8]) cancels in softmax.

  float* ctx  = (float*)d_out;                         // [256*512]
  float* wout = (float*)d_out + (size_t)kB * kQ * kH;  // [256*1024]

  float* qp   = (float*)d_ws;                          // 512 KB
  float* kp   = qp + (size_t)kB * kQ * kH;             // 8 MB
  float* part = kp;  // aliases kp (dead after score); 16*0.5 MB = 8 MB

  proj_dual<<<dim3(8, 68), 64, 0, stream>>>(key_, Wk, bk, kp, query, Wq, bq, qp);
  score_kernel<<<1024, 256, 0, stream>>>(qp, kp, we, wout);
  softmax_kernel<<<kB * kQ, 256, 0, stream>>>(wout);
  context_kernel<<<256, 256, 0, stream>>>(wout, value, part);
  reduce_kernel<<<128, 256, 0, stream>>>(part, ctx);
}

// Round 8
// 190.423 us; speedup vs baseline: 1.1844x; 1.1844x over previous
//
#include <hip/hip_runtime.h>

// SoftAttention: B=4, Q=64, S=1024, H=512, fp32.
// out = [context (B*Q*H)] ++ [weights (B*Q*S)]
// ws: qp [256*512] at 0; kp [4096*512] at +512KB; context partials alias kp.
// qp/kp hold (2*log2e)*(X@W+b): score term = exp2(qp+kp) = exp(2*(q+k)).
// Sum(we) and be are (q,s)-independent -> cancel in softmax -> dropped.
// r5 lesson: NO global atomics for partial sums (memory-side RMW).
// r7 lesson: 1 wave/SIMD cannot hide LDS/global latency; keep >=2 waves/SIMD.

constexpr int kB = 4;
constexpr int kQ = 64;
constexpr int kS = 1024;
constexpr int kH = 512;
constexpr float kScale = 2.8853900817779268f;  // 2*log2(e)

// ---------------------------------------------------------------------------
// Projection (r4 structure, best measured 58us): Y = kScale*(X@W + bias).
// 64x64 tile, 256 thr, 4x4 acc/thread, K-chunks of 32 double-buffered.
// grid = (8 col-tiles, 68 row-tiles: 64 kp + 4 qp)
// ---------------------------------------------------------------------------
constexpr int kLdsStride = 68;

__global__ __launch_bounds__(256, 4) void proj_dual(
    const float* __restrict__ Xk, const float* __restrict__ Wk,
    const float* __restrict__ bk, float* __restrict__ Yk,
    const float* __restrict__ Xq, const float* __restrict__ Wq,
    const float* __restrict__ bq, float* __restrict__ Yq) {
  __shared__ __align__(16) float As[2][32 * kLdsStride];  // [k][row]
  __shared__ __align__(16) float Bs[2][32 * kLdsStride];  // [k][col]
  const int t = threadIdx.x;
  const int ct = blockIdx.x;  // 0..7
  int rt = blockIdx.y;        // 0..67
  const float *X, *W, *bias;
  float* Y;
  if (rt < 64) {
    X = Xk + (size_t)rt * 64 * kH; W = Wk; bias = bk; Y = Yk + (size_t)rt * 64 * kH;
  } else {
    rt -= 64;
    X = Xq + (size_t)rt * 64 * kH; W = Wq; bias = bq; Y = Yq + (size_t)rt * 64 * kH;
  }

  const int a_row = t & 63;
  const int a_k0 = (t >> 6) * 8;
  const int b_kl = t >> 4;
  const int b_c = (t & 15) * 4;
  const int cbase = ct * 64;
  const int r0 = (t >> 4) * 4;
  const int c0 = (t & 15) * 4;

  float4 pa[2], pb[2];

  auto gload = [&](int kb) {
    const float* xp = X + (size_t)a_row * kH + kb + a_k0;
    pa[0] = *(const float4*)(xp + 0);
    pa[1] = *(const float4*)(xp + 4);
#pragma unroll
    for (int p = 0; p < 2; p++)
      pb[p] = *(const float4*)(W + (size_t)(kb + p * 16 + b_kl) * kH + cbase + b_c);
  };

  auto lwrite = [&](int buf) {
    float* a = As[buf];
#pragma unroll
    for (int j = 0; j < 2; j++) {
      a[(a_k0 + 4 * j + 0) * kLdsStride + a_row] = pa[j].x;
      a[(a_k0 + 4 * j + 1) * kLdsStride + a_row] = pa[j].y;
      a[(a_k0 + 4 * j + 2) * kLdsStride + a_row] = pa[j].z;
      a[(a_k0 + 4 * j + 3) * kLdsStride + a_row] = pa[j].w;
    }
    float* b = Bs[buf];
#pragma unroll
    for (int p = 0; p < 2; p++)
      *(float4*)(b + (p * 16 + b_kl) * kLdsStride + b_c) = pb[p];
  };

  float4 acc0 = {0,0,0,0}, acc1 = {0,0,0,0}, acc2 = {0,0,0,0}, acc3 = {0,0,0,0};

  gload(0);
  lwrite(0);
  __syncthreads();

  for (int kc = 0; kc < 16; kc++) {
    if (kc < 15) gload((kc + 1) * 32);

    const float* a = As[kc & 1];
    const float* b = Bs[kc & 1];
#pragma unroll 8
    for (int kk = 0; kk < 32; kk++) {
      float4 av = *(const float4*)(a + kk * kLdsStride + r0);
      float4 bv = *(const float4*)(b + kk * kLdsStride + c0);
      acc0.x = fmaf(av.x, bv.x, acc0.x); acc0.y = fmaf(av.x, bv.y, acc0.y);
      acc0.z = fmaf(av.x, bv.z, acc0.z); acc0.w = fmaf(av.x, bv.w, acc0.w);
      acc1.x = fmaf(av.y, bv.x, acc1.x); acc1.y = fmaf(av.y, bv.y, acc1.y);
      acc1.z = fmaf(av.y, bv.z, acc1.z); acc1.w = fmaf(av.y, bv.w, acc1.w);
      acc2.x = fmaf(av.z, bv.x, acc2.x); acc2.y = fmaf(av.z, bv.y, acc2.y);
      acc2.z = fmaf(av.z, bv.z, acc2.z); acc2.w = fmaf(av.z, bv.w, acc2.w);
      acc3.x = fmaf(av.w, bv.x, acc3.x); acc3.y = fmaf(av.w, bv.y, acc3.y);
      acc3.z = fmaf(av.w, bv.z, acc3.z); acc3.w = fmaf(av.w, bv.w, acc3.w);
    }

    if (kc < 15) {
      __syncthreads();
      lwrite((kc + 1) & 1);
      __syncthreads();
    }
  }

  float4 bv = *(const float4*)(bias + cbase + c0);
  float* yp = Y + (size_t)r0 * kH + cbase + c0;
  float4 o;
  o.x = kScale*(acc0.x+bv.x); o.y = kScale*(acc0.y+bv.y);
  o.z = kScale*(acc0.z+bv.z); o.w = kScale*(acc0.w+bv.w);
  *(float4*)(yp + 0 * kH) = o;
  o.x = kScale*(acc1.x+bv.x); o.y = kScale*(acc1.y+bv.y);
  o.z = kScale*(acc1.z+bv.z); o.w = kScale*(acc1.w+bv.w);
  *(float4*)(yp + 1 * kH) = o;
  o.x = kScale*(acc2.x+bv.x); o.y = kScale*(acc2.y+bv.y);
  o.z = kScale*(acc2.z+bv.z); o.w = kScale*(acc2.w+bv.w);
  *(float4*)(yp + 2 * kH) = o;
  o.x = kScale*(acc3.x+bv.x); o.y = kScale*(acc3.y+bv.y);
  o.z = kScale*(acc3.z+bv.z); o.w = kScale*(acc3.w+bv.w);
  *(float4*)(yp + 3 * kH) = o;
}

// ---------------------------------------------------------------------------
// Scores (shifted; constants dropped) -> sout[bq][s].
// score' = sum_h (-2*we[h]) * rcp(1 + exp2(qp[q][h] + kp[s][h]))
// grid = 1024 (b x 4 q-tiles x 64 s-tiles), 256 thr = 4 waves.
// Wave w owns h in [w*128, w*128+128); lane = (s_loc = l&15, hq = l>>4);
// each lane accumulates 32 h x 16 q IN-REGISTER (no shfl in hot loop).
// LDS padded per-32-h so qpl reads are conflict-free 16-lane broadcasts.
// ---------------------------------------------------------------------------
__global__ __launch_bounds__(256, 2) void score_kernel(
    const float* __restrict__ qp, const float* __restrict__ kp,
    const float* __restrict__ we, float* __restrict__ sout) {
  // qpl[q][h]:  idx = q*592 + (h>>5)*36 + (h&31)      (37.9 KB)
  // kptl[h][s]: idx = (h>>5)*548 + (h&31)*17 + s      (35.1 KB)
  // we2l[h]:    idx = (h>>5)*36 + (h&31)              (2.3 KB)
  __shared__ float qpl[16 * 592];
  __shared__ float kptl[16 * 548];
  __shared__ float we2l[576];
  __shared__ float red[4 * 256];

  const int bx = blockIdx.x;
  const int b = bx >> 8, qt = (bx >> 6) & 3, st = bx & 63;
  const int t = threadIdx.x;
  const int w = t >> 6, lane = t & 63;
  const int q0 = qt * 16, s0 = st * 16;

  {  // stage qp tile [16 q][512 h]
    const int q = t >> 4, hb = (t & 15) * 32;
    const float* src = qp + (size_t)(b * kQ + q0 + q) * kH + hb;
    float* dst = qpl + q * 592 + (hb >> 5) * 36;
#pragma unroll
    for (int jj = 0; jj < 8; jj++)
      *(float4*)(dst + jj * 4) = *(const float4*)(src + jj * 4);
  }
  {  // stage kp^T tile [512 h][16 s]
    const int s = t & 15, hc = t >> 4;
    const float* src = kp + (size_t)(b * kS + s0 + s) * kH + hc * 32;
    float* dst = kptl + hc * 548 + s;
#pragma unroll
    for (int jj = 0; jj < 8; jj++) {
      float4 v = *(const float4*)(src + jj * 4);
      dst[(jj * 4 + 0) * 17] = v.x;
      dst[(jj * 4 + 1) * 17] = v.y;
      dst[(jj * 4 + 2) * 17] = v.z;
      dst[(jj * 4 + 3) * 17] = v.w;
    }
  }
  {  // stage we2 = -2*we (h0 even => h0,h0+1 share a 32-group)
    const int h0 = t * 2;
    float2 v = *(const float2*)(we + h0);
    float* dst = we2l + (h0 >> 5) * 36 + (h0 & 31);
    dst[0] = -2.f * v.x;
    dst[1] = -2.f * v.y;
  }
  __syncthreads();

  const int s_loc = lane & 15, hq = lane >> 4;
  const int hg = w * 4 + hq;  // h>>5 for this lane, 0..15
  const float* kbase = kptl + hg * 548 + s_loc;
  const float* wbase = we2l + hg * 36;
  const float* qbase = qpl + hg * 36;

  float acc[16];
#pragma unroll
  for (int q = 0; q < 16; q++) acc[q] = 0.f;

#pragma unroll 2
  for (int j = 0; j < 32; j++) {
    float kv = kbase[j * 17];
    float wv = wbase[j];
    const float* qb = qbase + j;
#pragma unroll
    for (int q = 0; q < 16; q++) {
      float e = exp2f(qb[q * 592] + kv);
      acc[q] = fmaf(wv, __builtin_amdgcn_rcpf(1.f + e), acc[q]);
    }
  }

  // reduce over hq (lanes l, l^16, l^32, l^48)
#pragma unroll
  for (int q = 0; q < 16; q++) {
    acc[q] += __shfl_xor(acc[q], 16);
    acc[q] += __shfl_xor(acc[q], 32);
  }
  if (lane < 16) {
    float* rr = red + w * 256 + lane;
#pragma unroll
    for (int q = 0; q < 16; q++) rr[q * 16] = acc[q];
  }
  __syncthreads();
  {  // cross-wave reduce + store: t = (q = t>>4, s = t&15)
    const int q = t >> 4, s = t & 15;
    const int i = q * 16 + s;
    float sum = red[i] + red[256 + i] + red[512 + i] + red[768 + i];
    sout[(size_t)(b * kQ + q0 + q) * kS + s0 + s] = sum;
  }
}

// ---------------------------------------------------------------------------
// Softmax in place on wout rows of 1024.  grid = 256 rows, 256 thr.
// ---------------------------------------------------------------------------
__global__ __launch_bounds__(256) void softmax_kernel(float* __restrict__ wout) {
  __shared__ float redm[4];
  __shared__ float reds[4];
  const int row = blockIdx.x;
  const int t = threadIdx.x, wave = t >> 6, lane = t & 63;
  float4* rp = (float4*)(wout + (size_t)row * kS);
  float4 v = rp[t];

  float m = fmaxf(fmaxf(v.x, v.y), fmaxf(v.z, v.w));
#pragma unroll
  for (int off = 32; off; off >>= 1) m = fmaxf(m, __shfl_xor(m, off));
  if (lane == 0) redm[wave] = m;
  __syncthreads();
  m = fmaxf(fmaxf(redm[0], redm[1]), fmaxf(redm[2], redm[3]));

  float4 e;
  e.x = __expf(v.x - m); e.y = __expf(v.y - m);
  e.z = __expf(v.z - m); e.w = __expf(v.w - m);
  float sum = e.x + e.y + e.z + e.w;
#pragma unroll
  for (int off = 32; off; off >>= 1) sum += __shfl_xor(sum, off);
  if (lane == 0) reds[wave] = sum;
  __syncthreads();
  sum = reds[0] + reds[1] + reds[2] + reds[3];
  float inv = 1.f / sum;
  e.x *= inv; e.y *= inv; e.z *= inv; e.w *= inv;
  rp[t] = e;
}

// ---------------------------------------------------------------------------
// Context partials: part[sc][bq][h] = sum_{s in 64-chunk} w[bq][s]*value[b][s][h]
// grid = 512 (b x 2 h-chunks x 4 q-chunks x 16 s-chunks), 256 thr.
// ---------------------------------------------------------------------------
__global__ __launch_bounds__(256) void context_kernel(
    const float* __restrict__ wout, const float* __restrict__ value,
    float* __restrict__ part) {
  __shared__ __align__(16) float wt[64][16];
  const int bx = blockIdx.x;
  const int sc = bx & 15, qc = (bx >> 4) & 3, hc = (bx >> 6) & 1, b = bx >> 7;
  const int t = threadIdx.x;
  const int s0 = sc * 64, q0 = qc * 16;

  {  // load + transpose weights tile [16 q][64 s] -> wt[s][q]
    const int q_l = t & 15;
    const int sseg = (t >> 4) * 4;
    float4 u = *(const float4*)(wout + (size_t)(b * kQ + q0 + q_l) * kS + s0 + sseg);
    wt[sseg + 0][q_l] = u.x; wt[sseg + 1][q_l] = u.y;
    wt[sseg + 2][q_l] = u.z; wt[sseg + 3][q_l] = u.w;
  }
  __syncthreads();

  const int h = hc * 256 + t;
  const float* vb = value + ((size_t)b * kS + s0) * kH + h;
  float acc[16];
#pragma unroll
  for (int i = 0; i < 16; i++) acc[i] = 0.f;

#pragma unroll 8
  for (int s = 0; s < 64; s++) {
    float v = vb[(size_t)s * kH];
    const float4* wrow = (const float4*)&wt[s][0];
    float4 a0 = wrow[0], a1 = wrow[1], a2 = wrow[2], a3 = wrow[3];
    acc[0]  = fmaf(a0.x, v, acc[0]);  acc[1]  = fmaf(a0.y, v, acc[1]);
    acc[2]  = fmaf(a0.z, v, acc[2]);  acc[3]  = fmaf(a0.w, v, acc[3]);
    acc[4]  = fmaf(a1.x, v, acc[4]);  acc[5]  = fmaf(a1.y, v, acc[5]);
    acc[6]  = fmaf(a1.z, v, acc[6]);  acc[7]  = fmaf(a1.w, v, acc[7]);
    acc[8]  = fmaf(a2.x, v, acc[8]);  acc[9]  = fmaf(a2.y, v, acc[9]);
    acc[10] = fmaf(a2.z, v, acc[10]); acc[11] = fmaf(a2.w, v, acc[11]);
    acc[12] = fmaf(a3.x, v, acc[12]); acc[13] = fmaf(a3.y, v, acc[13]);
    acc[14] = fmaf(a3.z, v, acc[14]); acc[15] = fmaf(a3.w, v, acc[15]);
  }

  float* pp = part + (size_t)sc * kB * kQ * kH;
#pragma unroll
  for (int i = 0; i < 16; i++)
    pp[(size_t)(b * kQ + q0 + i) * kH + h] = acc[i];
}

// ctx[i] = sum over 16 s-chunk partials.  grid = 128, 256 thr.
__global__ __launch_bounds__(256) void reduce_kernel(
    const float* __restrict__ part, float* __restrict__ ctx) {
  const int i = blockIdx.x * 256 + threadIdx.x;  // float4 index, 32768 total
  float4 a = {0, 0, 0, 0};
#pragma unroll
  for (int p = 0; p < 16; p++) {
    float4 v = ((const float4*)(part + (size_t)p * kB * kQ * kH))[i];
    a.x += v.x; a.y += v.y; a.z += v.z; a.w += v.w;
  }
  ((float4*)ctx)[i] = a;
}

extern "C" void kernel_launch(void* const* d_in, const int* in_sizes, int n_in,
                              void* d_out, int out_size, void* d_ws,
                              size_t ws_size, hipStream_t stream) {
  const float* query = (const float*)d_in[0];
  const float* key_  = (const float*)d_in[1];
  const float* value = (const float*)d_in[2];
  const float* Wq    = (const float*)d_in[3];
  const float* bq    = (const float*)d_in[4];
  const float* Wk    = (const float*)d_in[5];
  const float* bk    = (const float*)d_in[6];
  const float* we    = (const float*)d_in[7];
  // be (d_in[8]) and sum(we) cancel in softmax.

  float* ctx  = (float*)d_out;                         // [256*512]
  float* wout = (float*)d_out + (size_t)kB * kQ * kH;  // [256*1024]

  float* qp   = (float*)d_ws;                          // 512 KB
  float* kp   = qp + (size_t)kB * kQ * kH;             // 8 MB
  float* part = kp;  // aliases kp (dead after score); 16*0.5 MB = 8 MB

  proj_dual<<<dim3(8, 68), 256, 0, stream>>>(key_, Wk, bk, kp, query, Wq, bq, qp);
  score_kernel<<<1024, 256, 0, stream>>>(qp, kp, we, wout);
  softmax_kernel<<<kB * kQ, 256, 0, stream>>>(wout);
  context_kernel<<<512, 256, 0, stream>>>(wout, value, part);
  reduce_kernel<<<128, 256, 0, stream>>>(part, ctx);
}